// Round 20
// baseline (311.202 us; speedup 1.0000x reference)
//
#include <hip/hip_runtime.h>
#include <hip/hip_fp16.h>

typedef _Float16 f16x8 __attribute__((ext_vector_type(8)));
typedef float f32x4 __attribute__((ext_vector_type(4)));
typedef unsigned u32x4 __attribute__((ext_vector_type(4)));
typedef unsigned short u16;

#define DN 128   // node in props
#define DE 32    // edge in props
#define LE 16    // latent edges (channels)
#define LN 64    // latent nodes
#define DOUT 128 // out props
#define ST 1032  // LDS row stride in fp16 (2064 B, 16B-aligned)

__device__ inline u16 f2h(float f) { return __half_as_ushort(__float2half(f)); }
__device__ inline float h2f(u16 u) { return __half2float(__ushort_as_half(u)); }
__device__ inline unsigned pack2h(float lo, float hi) {
  return (unsigned)f2h(lo) | ((unsigned)f2h(hi) << 16);
}
__device__ inline void unp2(unsigned u, float& a, float& b) {
  __half2 p = *reinterpret_cast<__half2*>(&u);
  a = __half2float(__low2half(p));
  b = __half2float(__high2half(p));
}
__device__ inline __half2 u2h2(unsigned u) {
  return *reinterpret_cast<__half2*>(&u);
}
__device__ inline unsigned h22u(__half2 h) {
  return *reinterpret_cast<unsigned*>(&h);
}
__device__ inline u16 hmul3(u16 a, u16 b, u16 c) {
  __half t = __hmul(__hmul(__ushort_as_half(a), __ushort_as_half(b)),
                    __ushort_as_half(c));
  return __half_as_ushort(t);
}

// ---------------- weight packing (device body) ----------------
__device__ inline void packb_one(const float* __restrict__ W, u16* __restrict__ Bp,
                                 int idx, int K, int NCOL) {
  int KT = K >> 5;
  int lane = idx & 63;
  int rest = idx >> 6;
  int kt = rest % KT, nt = rest / KT;
  int col = nt * 16 + (lane & 15);
  int kb = kt * 32 + (lane >> 4) * 8;
  u16* dst = Bp + (size_t)idx * 8;
#pragma unroll
  for (int i = 0; i < 8; ++i) dst[i] = f2h(W[(size_t)(kb + i) * NCOL + col]);
}

// count + per-edge rank (the ONLY atomic pass; rank store is coalesced)
__global__ __launch_bounds__(256) void k_count(const int* __restrict__ ei,
    int* __restrict__ cnt, int* __restrict__ rank, int E) {
  int e = blockIdx.x * 256 + threadIdx.x;
  if (e < E) rank[e] = atomicAdd(&cnt[ei[E + e]], 1);
}

// block 0: single-block exclusive scan cnt->offs; blocks >=1: pack both weight mats
__global__ __launch_bounds__(1024) void k_scan_packb(const int* __restrict__ cnt,
    int* __restrict__ offs, int N,
    const float* __restrict__ Wg, u16* __restrict__ WgP,
    const float* __restrict__ Wn, u16* __restrict__ WnP) {
  const int totA = (DN / 32) * (LN / 16) * 64;          // 1024
  const int totB = ((LE * LN) / 32) * (DOUT / 16) * 64; // 16384
  if (blockIdx.x != 0) {
    int idx = (blockIdx.x - 1) * 1024 + threadIdx.x;
    if (idx < totA) packb_one(Wg, WgP, idx, DN, LN);
    else if (idx < totA + totB) packb_one(Wn, WnP, idx - totA, LE * LN, DOUT);
    return;
  }
  __shared__ int wsum[16];
  int t = threadIdx.x;
  int chunk = (N + 1023) >> 10;
  int s0 = t * chunk;
  int s1 = min(s0 + chunk, N);
  int s = 0;
  for (int i = s0; i < s1; ++i) s += cnt[i];
  int lane = t & 63, wid = t >> 6;
  int v = s;
#pragma unroll
  for (int d = 1; d < 64; d <<= 1) {
    int u = __shfl_up(v, d);
    if (lane >= d) v += u;
  }
  if (lane == 63) wsum[wid] = v;
  __syncthreads();
  if (t == 0) {
    int run = 0;
    for (int w = 0; w < 16; ++w) { int xv = wsum[w]; wsum[w] = run; run += xv; }
  }
  __syncthreads();
  int run = v - s + wsum[wid];  // exclusive prefix for this thread
  for (int i = s0; i < s1; ++i) { offs[i] = run; run += cnt[i]; }
  if (s1 == N && s0 < N) offs[N] = run;
}

// ---------------- GEMM body ----------
template <int K, int NCOL, int MT, bool FIN, bool AF32, bool OUT16>
__device__ inline void gemm_body(int bid, const void* __restrict__ Av,
    const u16* __restrict__ Bp, const float* __restrict__ bias,
    void* __restrict__ outv, int M) {
  constexpr int NT = NCOL / 16;
  constexpr int KT = K / 32;
  const u16* A16 = (const u16*)Av;
  const float* A32 = (const float*)Av;
  int lane = threadIdx.x & 63;
  int wid = threadIdx.x >> 6;
  int m0 = bid * (MT * 64) + wid * (MT * 16);
  f32x4 acc[MT][NT];
#pragma unroll
  for (int mt = 0; mt < MT; ++mt)
#pragma unroll
    for (int nt = 0; nt < NT; ++nt) {
      acc[mt][nt][0] = 0.f; acc[mt][nt][1] = 0.f;
      acc[mt][nt][2] = 0.f; acc[mt][nt][3] = 0.f;
    }
  int rr[MT]; bool vv[MT];
#pragma unroll
  for (int mt = 0; mt < MT; ++mt) {
    rr[mt] = m0 + mt * 16 + (lane & 15);
    vv[mt] = rr[mt] < M;
  }
  int ko = (lane >> 4) * 8;
#pragma unroll 8
  for (int kt = 0; kt < KT; ++kt) {
    f16x8 a[MT];
#pragma unroll
    for (int mt = 0; mt < MT; ++mt) {
#pragma unroll
      for (int i = 0; i < 8; ++i) a[mt][i] = (_Float16)0.f;
      if constexpr (AF32) {
        if (vv[mt]) {
          const float4* p4 = (const float4*)(A32 + (size_t)rr[mt] * K + ko + kt * 32);
          float4 u0 = p4[0], u1 = p4[1];
          a[mt][0]=(_Float16)u0.x; a[mt][1]=(_Float16)u0.y;
          a[mt][2]=(_Float16)u0.z; a[mt][3]=(_Float16)u0.w;
          a[mt][4]=(_Float16)u1.x; a[mt][5]=(_Float16)u1.y;
          a[mt][6]=(_Float16)u1.z; a[mt][7]=(_Float16)u1.w;
        }
      } else {
        if (vv[mt]) a[mt] = *(const f16x8*)(A16 + (size_t)rr[mt] * K + ko + kt * 32);
      }
    }
#pragma unroll
    for (int nt = 0; nt < NT; ++nt) {
      f16x8 b = *(const f16x8*)(Bp + ((size_t)(nt * KT + kt) * 64 + lane) * 8);
#pragma unroll
      for (int mt = 0; mt < MT; ++mt)
        acc[mt][nt] = __builtin_amdgcn_mfma_f32_16x16x32_f16(a[mt], b, acc[mt][nt], 0, 0, 0);
    }
  }
  int col0 = lane & 15;
#pragma unroll
  for (int mt = 0; mt < MT; ++mt) {
    int rb = m0 + mt * 16 + ((lane >> 4) << 2);
#pragma unroll
    for (int nt = 0; nt < NT; ++nt) {
      int c = nt * 16 + col0;
      float bb = FIN ? bias[c] : 0.f;
#pragma unroll
      for (int r = 0; r < 4; ++r) {
        int row = rb + r;
        if (row < M) {
          float vvv = acc[mt][nt][r] + bb;
          if (FIN) vvv = fmaxf(vvv, 0.f);
          if constexpr (OUT16) ((u16*)outv)[(size_t)row * NCOL + c] = f2h(vvv);
          else ((float*)outv)[(size_t)row * NCOL + c] = vvv;
        }
      }
    }
  }
}

// MERGED + INTERLEAVED: every 5th block runs gemm1; the rest run CSR-fill+edge-MLP.
__global__ __launch_bounds__(256) void k_fill_gemm1(const float* __restrict__ ea,
    const float* __restrict__ We, const float* __restrict__ be,
    const int* __restrict__ ei, const int* __restrict__ rank,
    const int* __restrict__ offs,
    int* __restrict__ src, u16* __restrict__ wh, int E,
    const float* __restrict__ x, const u16* __restrict__ WgP,
    u16* __restrict__ xwh, int N, int GB) {
  int bid = blockIdx.x;
  int g = bid / 5;
  if ((bid % 5 == 0) && g < GB) {
    gemm_body<DN, LN, 1, false, true, true>(g, x, WgP, nullptr, xwh, N);
    return;
  }
  int ngem = min((bid + 4) / 5, GB);   // gemm blocks at indices < bid
  int e = (bid - ngem) * 256 + threadIdx.x;
  if (e >= E) return;
  const float4* a4 = (const float4*)(ea + (size_t)e * DE);
  float a[DE];
#pragma unroll
  for (int j = 0; j < DE / 4; ++j) {
    float4 v = a4[j];
    a[4*j] = v.x; a[4*j+1] = v.y; a[4*j+2] = v.z; a[4*j+3] = v.w;
  }
  float acc[LE];
#pragma unroll
  for (int l = 0; l < LE; ++l) acc[l] = be[l];
#pragma unroll
  for (int k = 0; k < DE; ++k) {
    float av = a[k];
#pragma unroll
    for (int l = 0; l < LE; ++l) acc[l] = fmaf(av, We[k * LE + l], acc[l]);
  }
  uint4 o0, o1;
  o0.x = pack2h(fmaxf(acc[0], 0.f), fmaxf(acc[1], 0.f));
  o0.y = pack2h(fmaxf(acc[2], 0.f), fmaxf(acc[3], 0.f));
  o0.z = pack2h(fmaxf(acc[4], 0.f), fmaxf(acc[5], 0.f));
  o0.w = pack2h(fmaxf(acc[6], 0.f), fmaxf(acc[7], 0.f));
  o1.x = pack2h(fmaxf(acc[8], 0.f), fmaxf(acc[9], 0.f));
  o1.y = pack2h(fmaxf(acc[10], 0.f), fmaxf(acc[11], 0.f));
  o1.z = pack2h(fmaxf(acc[12], 0.f), fmaxf(acc[13], 0.f));
  o1.w = pack2h(fmaxf(acc[14], 0.f), fmaxf(acc[15], 0.f));
  int c = ei[E + e];
  int pos = offs[c] + rank[e];
  src[pos] = ei[e];
  uint4* o4 = (uint4*)(wh + (size_t)pos * LE);
  o4[0] = o0; o4[1] = o1;
}

// dinvh[n,l] = fp16(rsqrt(1 + seg-sum of wh)); 16 nodes/block
__global__ __launch_bounds__(256) void k_dinv(const u16* __restrict__ wh,
    const int* __restrict__ offs, u16* __restrict__ dinvh, int N) {
  int t = threadIdx.x;
  int n = blockIdx.x * 16 + (t >> 4);
  int l = t & 15;
  if (n >= N) return;
  int i0 = offs[n], i1 = offs[n + 1];
  float s = 1.0f;  // self loop weight
  for (int i = i0; i < i1; ++i) s += h2f(wh[(size_t)i * LE + l]);
  dinvh[(size_t)n * LE + l] = f2h(rsqrtf(s));
}

// epilogue: write feats row r (node n) into LDS, swizzled for phase-2 MFMA reads
__device__ inline void lds_epilogue(int n, int r, int l, int colb, const __half2* acc,
    const u16* __restrict__ dinvh, const u16* __restrict__ xwh,
    const float* __restrict__ bgcn, u16* __restrict__ S) {
  float dn = h2f(dinvh[(size_t)n * LE + l]);
  float dn2 = dn * dn;
  const u32x4* xs4 = (const u32x4*)(xwh + (size_t)n * LN + colb);
  u32x4 m0 = xs4[0], m1 = xs4[1];
  const f32x4* bgp = (const f32x4*)(bgcn + colb);
  f32x4 b0 = bgp[0], b1 = bgp[1], b2 = bgp[2], b3 = bgp[3];
  float xv[16];
  unp2(m0[0], xv[0], xv[1]);   unp2(m0[1], xv[2], xv[3]);
  unp2(m0[2], xv[4], xv[5]);   unp2(m0[3], xv[6], xv[7]);
  unp2(m1[0], xv[8], xv[9]);   unp2(m1[1], xv[10], xv[11]);
  unp2(m1[2], xv[12], xv[13]); unp2(m1[3], xv[14], xv[15]);
  float av[16];
  unp2(h22u(acc[0]), av[0], av[1]);   unp2(h22u(acc[1]), av[2], av[3]);
  unp2(h22u(acc[2]), av[4], av[5]);   unp2(h22u(acc[3]), av[6], av[7]);
  unp2(h22u(acc[4]), av[8], av[9]);   unp2(h22u(acc[5]), av[10], av[11]);
  unp2(h22u(acc[6]), av[12], av[13]); unp2(h22u(acc[7]), av[14], av[15]);
  float bgv[16] = {b0[0],b0[1],b0[2],b0[3],b1[0],b1[1],b1[2],b1[3],
                   b2[0],b2[1],b2[2],b2[3],b3[0],b3[1],b3[2],b3[3]};
  float ov[16];
#pragma unroll
  for (int j = 0; j < 16; ++j) ov[j] = bgv[j] + dn * av[j] + dn2 * xv[j];
  u32x4 o0, o1;
  o0[0] = pack2h(ov[0], ov[1]);   o0[1] = pack2h(ov[2], ov[3]);
  o0[2] = pack2h(ov[4], ov[5]);   o0[3] = pack2h(ov[6], ov[7]);
  o1[0] = pack2h(ov[8], ov[9]);   o1[1] = pack2h(ov[10], ov[11]);
  o1[2] = pack2h(ov[12], ov[13]); o1[3] = pack2h(ov[14], ov[15]);
  int off = l * 128 + colb * 2;
  int swz = (l & 7) << 4;
  char* rowp = (char*)(S + (size_t)r * ST);
  *(u32x4*)(rowp + (off ^ swz)) = o0;
  *(u32x4*)(rowp + ((off + 16) ^ swz)) = o1;
}

// CAS-based fp16x2 add into LDS (rare: only at node boundaries)
__device__ inline void cas_add_u32(unsigned* p, __half2 v) {
  unsigned cur = *(volatile unsigned*)p;
  unsigned assumed;
  do {
    assumed = cur;
    __half2 nw = __hadd2(u2h2(assumed), v);
    cur = atomicCAS(p, assumed, h22u(nw));
  } while (cur != assumed);
}
__device__ inline void lds_cas_add(u16* S, int r, int l, int colb, const __half2* acc) {
  char* rowp = (char*)(S + (size_t)r * ST);
  int off = l * 128 + colb * 2;
  int swz = (l & 7) << 4;
  unsigned* b0 = (unsigned*)(rowp + (off ^ swz));
  unsigned* b1 = (unsigned*)(rowp + ((off + 16) ^ swz));
#pragma unroll
  for (int j = 0; j < 4; ++j) cas_add_u32(b0 + j, acc[j]);
#pragma unroll
  for (int j = 0; j < 4; ++j) cas_add_u32(b1 + j, acc[4 + j]);
}

// MEGA v2: balanced gather. Phase 0: rows init = bias + dn^2*x. Phase 1: the
// block's 16 nodes span a CONTIGUOUS CSR range; split edges evenly across the
// 8 waves (perfect balance) — register-accumulate per current node, flush via
// LDS CAS-add only at node boundaries (~3/wave). Phase 2: MFMA output MLP.
__global__ __launch_bounds__(512) void k_mega(const int* __restrict__ src,
    const u16* __restrict__ wh, const u16* __restrict__ dinvh,
    const u16* __restrict__ xwh, const float* __restrict__ bgcn,
    const int* __restrict__ offs, const u16* __restrict__ WnP,
    const float* __restrict__ bn, float* __restrict__ y, int N) {
  __shared__ u16 S[16 * ST];  // 33,024 B
  int tid = threadIdx.x;
  int w = tid >> 6, lane = tid & 63;
  int l = lane & 15, g = lane >> 4;
  int colb = g * 16;
  int nblk = blockIdx.x * 16;
  __half2 acc[8];
#pragma unroll
  for (int j = 0; j < 8; ++j) acc[j] = u2h2(0u);
  // ---- phase 0: init rows 2w, 2w+1 (bias + self-loop term; acc = 0) ----
  {
    int r0 = 2 * w;
    int n0 = nblk + r0, n1 = n0 + 1;
    if (n0 < N) lds_epilogue(n0, r0, l, colb, acc, dinvh, xwh, bgcn, S);
    if (n1 < N) lds_epilogue(n1, r0 + 1, l, colb, acc, dinvh, xwh, bgcn, S);
  }
  __syncthreads();
  // ---- phase 1: balanced chunked gather ----
  int nEnd = min(nblk + 16, N);
  if (nblk < N) {
    int E0 = offs[nblk], E1 = offs[nEnd];
    int total = E1 - E0;
    int W = (total + 7) >> 3;
    int i = E0 + w * W;
    int iend = min(i + W, E1);
    if (i < iend) {
      // locate starting node (wave-uniform walk)
      int n = nblk;
      int nb = offs[n + 1];
      while (nb <= i) { ++n; nb = offs[n + 1]; }
      u16 dnl = dinvh[(size_t)n * LE + l];
      const u16* xb = xwh + colb;
      while (i < iend) {
        if (i >= nb) {  // node boundary: flush and advance
          lds_cas_add(S, n - nblk, l, colb, acc);
#pragma unroll
          for (int j = 0; j < 8; ++j) acc[j] = u2h2(0u);
          ++n; nb = offs[n + 1];
          dnl = dinvh[(size_t)n * LE + l];
          continue;
        }
        int lim = min(iend, nb);
        if (i + 1 < lim) {
          // two edges, same node
          int s0 = src[i], s1 = src[i + 1];
          u16 w0 = wh[(size_t)i * LE + l];
          u16 w1 = wh[(size_t)(i + 1) * LE + l];
          u16 d0 = dinvh[(size_t)s0 * LE + l];
          u16 d1 = dinvh[(size_t)s1 * LE + l];
          const u32x4* p0 = (const u32x4*)(xb + (size_t)s0 * LN);
          const u32x4* p1 = (const u32x4*)(xb + (size_t)s1 * LN);
          u32x4 r0a = p0[0], r0b = p0[1];
          u32x4 r1a = p1[0], r1b = p1[1];
          unsigned c0 = (unsigned)hmul3(w0, d0, dnl); c0 |= c0 << 16;
          unsigned c1 = (unsigned)hmul3(w1, d1, dnl); c1 |= c1 << 16;
          __half2 ch0 = u2h2(c0), ch1 = u2h2(c1);
          acc[0] = __hfma2(ch0, u2h2(r0a[0]), acc[0]);
          acc[1] = __hfma2(ch0, u2h2(r0a[1]), acc[1]);
          acc[2] = __hfma2(ch0, u2h2(r0a[2]), acc[2]);
          acc[3] = __hfma2(ch0, u2h2(r0a[3]), acc[3]);
          acc[4] = __hfma2(ch0, u2h2(r0b[0]), acc[4]);
          acc[5] = __hfma2(ch0, u2h2(r0b[1]), acc[5]);
          acc[6] = __hfma2(ch0, u2h2(r0b[2]), acc[6]);
          acc[7] = __hfma2(ch0, u2h2(r0b[3]), acc[7]);
          acc[0] = __hfma2(ch1, u2h2(r1a[0]), acc[0]);
          acc[1] = __hfma2(ch1, u2h2(r1a[1]), acc[1]);
          acc[2] = __hfma2(ch1, u2h2(r1a[2]), acc[2]);
          acc[3] = __hfma2(ch1, u2h2(r1a[3]), acc[3]);
          acc[4] = __hfma2(ch1, u2h2(r1b[0]), acc[4]);
          acc[5] = __hfma2(ch1, u2h2(r1b[1]), acc[5]);
          acc[6] = __hfma2(ch1, u2h2(r1b[2]), acc[6]);
          acc[7] = __hfma2(ch1, u2h2(r1b[3]), acc[7]);
          i += 2;
        } else {
          // single edge
          int s0 = src[i];
          u16 w0 = wh[(size_t)i * LE + l];
          u16 d0 = dinvh[(size_t)s0 * LE + l];
          const u32x4* p0 = (const u32x4*)(xb + (size_t)s0 * LN);
          u32x4 r0a = p0[0], r0b = p0[1];
          unsigned c0 = (unsigned)hmul3(w0, d0, dnl); c0 |= c0 << 16;
          __half2 ch0 = u2h2(c0);
          acc[0] = __hfma2(ch0, u2h2(r0a[0]), acc[0]);
          acc[1] = __hfma2(ch0, u2h2(r0a[1]), acc[1]);
          acc[2] = __hfma2(ch0, u2h2(r0a[2]), acc[2]);
          acc[3] = __hfma2(ch0, u2h2(r0a[3]), acc[3]);
          acc[4] = __hfma2(ch0, u2h2(r0b[0]), acc[4]);
          acc[5] = __hfma2(ch0, u2h2(r0b[1]), acc[5]);
          acc[6] = __hfma2(ch0, u2h2(r0b[2]), acc[6]);
          acc[7] = __hfma2(ch0, u2h2(r0b[3]), acc[7]);
          i += 1;
        }
      }
      lds_cas_add(S, n - nblk, l, colb, acc);  // final flush
    }
  }
  __syncthreads();
  // ---- phase 2: y[16,128] tile = S @ Wn; wave w owns cols w*16..w*16+15 ----
  f32x4 acc2;
  acc2[0] = 0.f; acc2[1] = 0.f; acc2[2] = 0.f; acc2[3] = 0.f;
  const char* arow = (const char*)(S + (size_t)(lane & 15) * ST);
#pragma unroll 8
  for (int kt = 0; kt < 32; ++kt) {
    int aoff = kt * 64 + g * 16;
    int key = ((aoff >> 7) & 7) << 4;
    f16x8 a = *(const f16x8*)(arow + (aoff ^ key));
    f16x8 b = *(const f16x8*)(WnP + ((size_t)(w * 32 + kt) * 64 + lane) * 8);
    acc2 = __builtin_amdgcn_mfma_f32_16x16x32_f16(a, b, acc2, 0, 0, 0);
  }
  int col = w * 16 + (lane & 15);
  float bb = bn[col];
  int rb = (lane >> 4) * 4;
#pragma unroll
  for (int r = 0; r < 4; ++r) {
    int row = nblk + rb + r;
    if (row < N) y[(size_t)row * DOUT + col] = fmaxf(acc2[r] + bb, 0.f);
  }
}

extern "C" void kernel_launch(void* const* d_in, const int* in_sizes, int n_in,
                              void* d_out, int out_size, void* d_ws, size_t ws_size,
                              hipStream_t stream) {
  const float* x  = (const float*)d_in[0];
  const int*   ei = (const int*)d_in[1];
  const float* ea = (const float*)d_in[2];
  const float* Wg = (const float*)d_in[3];
  const float* bg = (const float*)d_in[4];
  const float* We = (const float*)d_in[5];
  const float* be = (const float*)d_in[6];
  const float* Wn = (const float*)d_in[7];
  const float* bn = (const float*)d_in[8];
  float* outp = (float*)d_out;
  int N = in_sizes[0] / DN;  // 50000
  int E = in_sizes[1] / 2;   // 800000

  char* p = (char*)d_ws;
  auto carve = [&](size_t bytes) {
    char* r = p;
    p += (bytes + 255) & ~(size_t)255;
    return (void*)r;
  };
  u16*   wh    = (u16*)carve((size_t)E * LE * 2);    // CSR-ordered latent weights, fp16
  u16*   xwh   = (u16*)carve((size_t)N * LN * 2);    // xW in fp16
  u16*   dinvh = (u16*)carve((size_t)N * LE * 2);    // dinv fp16
  u16*   WnP   = (u16*)carve((size_t)(LE * LN) * DOUT * 2);
  u16*   WgP   = (u16*)carve((size_t)DN * LN * 2);
  int*   offs  = (int*)carve((size_t)(N + 1) * 4);
  int*   cnt   = (int*)carve((size_t)N * 4);
  int*   rank  = (int*)carve((size_t)E * 4);         // per-edge rank within dest
  int*   src   = (int*)carve((size_t)E * 4);

  hipMemsetAsync(cnt, 0, (size_t)N * 4, stream);

  // CSR histogram + per-edge rank (the only atomic pass)
  k_count<<<(E + 255) / 256, 256, 0, stream>>>(ei, cnt, rank, E);
  // scan (block 0) + pack both weight matrices (blocks 1..17)
  k_scan_packb<<<18, 1024, 0, stream>>>(cnt, offs, N, Wg, WgP, Wn, WnP);
  // interleaved: every 5th block = gemm1, rest = CSR-fill+edge-MLP
  int FB = (E + 255) / 256, GB = (N + 63) / 64;
  k_fill_gemm1<<<FB + GB, 256, 0, stream>>>(ea, We, be, ei, rank, offs,
                                            src, wh, E, x, WgP, xwh, N, GB);
  // weighted in-degree normalization
  k_dinv<<<(N + 15) / 16, 256, 0, stream>>>(wh, offs, dinvh, N);
  // fused aggregation + output MLP (balanced chunked gather)
  k_mega<<<(N + 15) / 16, 512, 0, stream>>>(src, wh, dinvh, xwh, bg, offs, WnP, bn, outp, N);
}

// Round 21
// 298.831 us; speedup vs baseline: 1.0414x; 1.0414x over previous
//
#include <hip/hip_runtime.h>
#include <hip/hip_fp16.h>

typedef _Float16 f16x8 __attribute__((ext_vector_type(8)));
typedef float f32x4 __attribute__((ext_vector_type(4)));
typedef unsigned u32x4 __attribute__((ext_vector_type(4)));
typedef unsigned short u16;

#define DN 128   // node in props
#define DE 32    // edge in props
#define LE 16    // latent edges (channels)
#define LN 64    // latent nodes
#define DOUT 128 // out props
#define ST 1032  // LDS row stride in fp16 (2064 B, 16B-aligned)

__device__ inline u16 f2h(float f) { return __half_as_ushort(__float2half(f)); }
__device__ inline float h2f(u16 u) { return __half2float(__ushort_as_half(u)); }
__device__ inline unsigned pack2h(float lo, float hi) {
  return (unsigned)f2h(lo) | ((unsigned)f2h(hi) << 16);
}
__device__ inline void unp2(unsigned u, float& a, float& b) {
  __half2 p = *reinterpret_cast<__half2*>(&u);
  a = __half2float(__low2half(p));
  b = __half2float(__high2half(p));
}
__device__ inline __half2 u2h2(unsigned u) {
  return *reinterpret_cast<__half2*>(&u);
}
__device__ inline unsigned h22u(__half2 h) {
  return *reinterpret_cast<unsigned*>(&h);
}
__device__ inline unsigned hmulu(u16 a, u16 b) {
  return (unsigned)__half_as_ushort(__hmul(__ushort_as_half(a), __ushort_as_half(b)));
}

// ---------------- weight packing (device body) ----------------
__device__ inline void packb_one(const float* __restrict__ W, u16* __restrict__ Bp,
                                 int idx, int K, int NCOL) {
  int KT = K >> 5;
  int lane = idx & 63;
  int rest = idx >> 6;
  int kt = rest % KT, nt = rest / KT;
  int col = nt * 16 + (lane & 15);
  int kb = kt * 32 + (lane >> 4) * 8;
  u16* dst = Bp + (size_t)idx * 8;
#pragma unroll
  for (int i = 0; i < 8; ++i) dst[i] = f2h(W[(size_t)(kb + i) * NCOL + col]);
}

// count + per-edge rank (the ONLY atomic pass; rank store is coalesced)
__global__ __launch_bounds__(256) void k_count(const int* __restrict__ ei,
    int* __restrict__ cnt, int* __restrict__ rank, int E) {
  int e = blockIdx.x * 256 + threadIdx.x;
  if (e < E) rank[e] = atomicAdd(&cnt[ei[E + e]], 1);
}

// block 0: single-block exclusive scan cnt->offs; blocks >=1: pack both weight mats
__global__ __launch_bounds__(1024) void k_scan_packb(const int* __restrict__ cnt,
    int* __restrict__ offs, int N,
    const float* __restrict__ Wg, u16* __restrict__ WgP,
    const float* __restrict__ Wn, u16* __restrict__ WnP) {
  const int totA = (DN / 32) * (LN / 16) * 64;          // 1024
  const int totB = ((LE * LN) / 32) * (DOUT / 16) * 64; // 16384
  if (blockIdx.x != 0) {
    int idx = (blockIdx.x - 1) * 1024 + threadIdx.x;
    if (idx < totA) packb_one(Wg, WgP, idx, DN, LN);
    else if (idx < totA + totB) packb_one(Wn, WnP, idx - totA, LE * LN, DOUT);
    return;
  }
  __shared__ int wsum[16];
  int t = threadIdx.x;
  int chunk = (N + 1023) >> 10;
  int s0 = t * chunk;
  int s1 = min(s0 + chunk, N);
  int s = 0;
  for (int i = s0; i < s1; ++i) s += cnt[i];
  int lane = t & 63, wid = t >> 6;
  int v = s;
#pragma unroll
  for (int d = 1; d < 64; d <<= 1) {
    int u = __shfl_up(v, d);
    if (lane >= d) v += u;
  }
  if (lane == 63) wsum[wid] = v;
  __syncthreads();
  if (t == 0) {
    int run = 0;
    for (int w = 0; w < 16; ++w) { int xv = wsum[w]; wsum[w] = run; run += xv; }
  }
  __syncthreads();
  int run = v - s + wsum[wid];  // exclusive prefix for this thread
  for (int i = s0; i < s1; ++i) { offs[i] = run; run += cnt[i]; }
  if (s1 == N && s0 < N) offs[N] = run;
}

// Fused CSR-fill + edge MLP, ATOMIC-FREE: pos = offs[dest] + rank[e]
__global__ __launch_bounds__(256) void k_fill_mlp(const float* __restrict__ ea,
    const float* __restrict__ We, const float* __restrict__ be,
    const int* __restrict__ ei, const int* __restrict__ rank,
    const int* __restrict__ offs,
    int* __restrict__ src, u16* __restrict__ wh, int E) {
  int e = blockIdx.x * 256 + threadIdx.x;
  if (e >= E) return;
  const float4* a4 = (const float4*)(ea + (size_t)e * DE);
  float a[DE];
#pragma unroll
  for (int j = 0; j < DE / 4; ++j) {
    float4 v = a4[j];
    a[4*j] = v.x; a[4*j+1] = v.y; a[4*j+2] = v.z; a[4*j+3] = v.w;
  }
  float acc[LE];
#pragma unroll
  for (int l = 0; l < LE; ++l) acc[l] = be[l];
#pragma unroll
  for (int k = 0; k < DE; ++k) {
    float av = a[k];
#pragma unroll
    for (int l = 0; l < LE; ++l) acc[l] = fmaf(av, We[k * LE + l], acc[l]);
  }
  uint4 o0, o1;
  o0.x = pack2h(fmaxf(acc[0], 0.f), fmaxf(acc[1], 0.f));
  o0.y = pack2h(fmaxf(acc[2], 0.f), fmaxf(acc[3], 0.f));
  o0.z = pack2h(fmaxf(acc[4], 0.f), fmaxf(acc[5], 0.f));
  o0.w = pack2h(fmaxf(acc[6], 0.f), fmaxf(acc[7], 0.f));
  o1.x = pack2h(fmaxf(acc[8], 0.f), fmaxf(acc[9], 0.f));
  o1.y = pack2h(fmaxf(acc[10], 0.f), fmaxf(acc[11], 0.f));
  o1.z = pack2h(fmaxf(acc[12], 0.f), fmaxf(acc[13], 0.f));
  o1.w = pack2h(fmaxf(acc[14], 0.f), fmaxf(acc[15], 0.f));
  int c = ei[E + e];
  int pos = offs[c] + rank[e];
  src[pos] = ei[e];
  uint4* o4 = (uint4*)(wh + (size_t)pos * LE);
  o4[0] = o0; o4[1] = o1;
}

// ---------------- GEMM body (used by dinv_gemm1 only) ----------
template <int K, int NCOL, int MT, bool FIN, bool AF32, bool OUT16>
__device__ inline void gemm_body(int bid, const void* __restrict__ Av,
    const u16* __restrict__ Bp, const float* __restrict__ bias,
    void* __restrict__ outv, int M) {
  constexpr int NT = NCOL / 16;
  constexpr int KT = K / 32;
  const u16* A16 = (const u16*)Av;
  const float* A32 = (const float*)Av;
  int lane = threadIdx.x & 63;
  int wid = threadIdx.x >> 6;
  int m0 = bid * (MT * 64) + wid * (MT * 16);
  f32x4 acc[MT][NT];
#pragma unroll
  for (int mt = 0; mt < MT; ++mt)
#pragma unroll
    for (int nt = 0; nt < NT; ++nt) {
      acc[mt][nt][0] = 0.f; acc[mt][nt][1] = 0.f;
      acc[mt][nt][2] = 0.f; acc[mt][nt][3] = 0.f;
    }
  int rr[MT]; bool vv[MT];
#pragma unroll
  for (int mt = 0; mt < MT; ++mt) {
    rr[mt] = m0 + mt * 16 + (lane & 15);
    vv[mt] = rr[mt] < M;
  }
  int ko = (lane >> 4) * 8;
#pragma unroll 8
  for (int kt = 0; kt < KT; ++kt) {
    f16x8 a[MT];
#pragma unroll
    for (int mt = 0; mt < MT; ++mt) {
#pragma unroll
      for (int i = 0; i < 8; ++i) a[mt][i] = (_Float16)0.f;
      if constexpr (AF32) {
        if (vv[mt]) {
          const float4* p4 = (const float4*)(A32 + (size_t)rr[mt] * K + ko + kt * 32);
          float4 u0 = p4[0], u1 = p4[1];
          a[mt][0]=(_Float16)u0.x; a[mt][1]=(_Float16)u0.y;
          a[mt][2]=(_Float16)u0.z; a[mt][3]=(_Float16)u0.w;
          a[mt][4]=(_Float16)u1.x; a[mt][5]=(_Float16)u1.y;
          a[mt][6]=(_Float16)u1.z; a[mt][7]=(_Float16)u1.w;
        }
      } else {
        if (vv[mt]) a[mt] = *(const f16x8*)(A16 + (size_t)rr[mt] * K + ko + kt * 32);
      }
    }
#pragma unroll
    for (int nt = 0; nt < NT; ++nt) {
      f16x8 b = *(const f16x8*)(Bp + ((size_t)(nt * KT + kt) * 64 + lane) * 8);
#pragma unroll
      for (int mt = 0; mt < MT; ++mt)
        acc[mt][nt] = __builtin_amdgcn_mfma_f32_16x16x32_f16(a[mt], b, acc[mt][nt], 0, 0, 0);
    }
  }
  int col0 = lane & 15;
#pragma unroll
  for (int mt = 0; mt < MT; ++mt) {
    int rb = m0 + mt * 16 + ((lane >> 4) << 2);
#pragma unroll
    for (int nt = 0; nt < NT; ++nt) {
      int c = nt * 16 + col0;
      float bb = FIN ? bias[c] : 0.f;
#pragma unroll
      for (int r = 0; r < 4; ++r) {
        int row = rb + r;
        if (row < M) {
          float vvv = acc[mt][nt][r] + bb;
          if (FIN) vvv = fmaxf(vvv, 0.f);
          if constexpr (OUT16) ((u16*)outv)[(size_t)row * NCOL + c] = f2h(vvv);
          else ((float*)outv)[(size_t)row * NCOL + c] = vvv;
        }
      }
    }
  }
}

// blocks [0,DB): dinvh; blocks [DB,..): gemm1 xwh = fp16(x @ Wg)
__global__ __launch_bounds__(256) void k_dinv_gemm1(const u16* __restrict__ wh,
    const int* __restrict__ offs, u16* __restrict__ dinvh, int N, int DB,
    const float* __restrict__ x, const u16* __restrict__ WgP, u16* __restrict__ xwh) {
  if ((int)blockIdx.x >= DB) {
    gemm_body<DN, LN, 1, false, true, true>(blockIdx.x - DB, x, WgP, nullptr, xwh, N);
    return;
  }
  int t = threadIdx.x;
  int n = blockIdx.x * 16 + (t >> 4);
  int l = t & 15;
  if (n >= N) return;
  int i0 = offs[n], i1 = offs[n + 1];
  float s = 1.0f;  // self loop weight
  for (int i = i0; i < i1; ++i) s += h2f(wh[(size_t)i * LE + l]);
  dinvh[(size_t)n * LE + l] = f2h(rsqrtf(s));
}

// epilogue: write feats row r (node n) into LDS, swizzled for phase-2 MFMA reads
__device__ inline void lds_epilogue(int n, int r, int l, int colb, const __half2* acc,
    const u16* __restrict__ dinvh, const u16* __restrict__ xwh,
    const float* __restrict__ bgcn, u16* __restrict__ S) {
  float dn = h2f(dinvh[(size_t)n * LE + l]);
  float dn2 = dn * dn;
  const u32x4* xs4 = (const u32x4*)(xwh + (size_t)n * LN + colb);
  u32x4 m0 = xs4[0], m1 = xs4[1];
  const f32x4* bgp = (const f32x4*)(bgcn + colb);
  f32x4 b0 = bgp[0], b1 = bgp[1], b2 = bgp[2], b3 = bgp[3];
  float xv[16];
  unp2(m0[0], xv[0], xv[1]);   unp2(m0[1], xv[2], xv[3]);
  unp2(m0[2], xv[4], xv[5]);   unp2(m0[3], xv[6], xv[7]);
  unp2(m1[0], xv[8], xv[9]);   unp2(m1[1], xv[10], xv[11]);
  unp2(m1[2], xv[12], xv[13]); unp2(m1[3], xv[14], xv[15]);
  float av[16];
  unp2(h22u(acc[0]), av[0], av[1]);   unp2(h22u(acc[1]), av[2], av[3]);
  unp2(h22u(acc[2]), av[4], av[5]);   unp2(h22u(acc[3]), av[6], av[7]);
  unp2(h22u(acc[4]), av[8], av[9]);   unp2(h22u(acc[5]), av[10], av[11]);
  unp2(h22u(acc[6]), av[12], av[13]); unp2(h22u(acc[7]), av[14], av[15]);
  float bgv[16] = {b0[0],b0[1],b0[2],b0[3],b1[0],b1[1],b1[2],b1[3],
                   b2[0],b2[1],b2[2],b2[3],b3[0],b3[1],b3[2],b3[3]};
  float ov[16];
#pragma unroll
  for (int j = 0; j < 16; ++j) ov[j] = bgv[j] + dn * av[j] + dn2 * xv[j];
  u32x4 o0, o1;
  o0[0] = pack2h(ov[0], ov[1]);   o0[1] = pack2h(ov[2], ov[3]);
  o0[2] = pack2h(ov[4], ov[5]);   o0[3] = pack2h(ov[6], ov[7]);
  o1[0] = pack2h(ov[8], ov[9]);   o1[1] = pack2h(ov[10], ov[11]);
  o1[2] = pack2h(ov[12], ov[13]); o1[3] = pack2h(ov[14], ov[15]);
  int off = l * 128 + colb * 2;
  int swz = (l & 7) << 4;
  char* rowp = (char*)(S + (size_t)r * ST);
  *(u32x4*)(rowp + (off ^ swz)) = o0;
  *(u32x4*)(rowp + ((off + 16) ^ swz)) = o1;
}

// MEGA: aggregation (2-chain gather per wave, static node ownership — the
// verified best of 10 gather variants) -> LDS -> output MLP MFMA.
__global__ __launch_bounds__(512) void k_mega(const int* __restrict__ src,
    const u16* __restrict__ wh, const u16* __restrict__ dinvh,
    const u16* __restrict__ xwh, const float* __restrict__ bgcn,
    const int* __restrict__ offs, const u16* __restrict__ WnP,
    const float* __restrict__ bn, float* __restrict__ y, int N) {
  __shared__ u16 S[16 * ST];  // 33,024 B
  int tid = threadIdx.x;
  int w = tid >> 6, lane = tid & 63;
  int l = lane & 15, g = lane >> 4;
  int colb = g * 16;
  int nblk = blockIdx.x * 16;
  int r0 = w * 2;
  int n0 = nblk + r0, n1 = n0 + 1;
  bool v0 = n0 < N, v1 = n1 < N;
  const u16* xb = xwh + colb;
  __half2 accA[8], accB[8];
#pragma unroll
  for (int j = 0; j < 8; ++j) { accA[j] = u2h2(0u); accB[j] = u2h2(0u); }
  int iA = v0 ? offs[n0] : 0, eA = v0 ? offs[n0 + 1] : 0;
  int iB = v1 ? offs[n1] : 0, eB = v1 ? offs[n1 + 1] : 0;
  int sA = (iA < eA) ? src[iA] : 0;
  int sB = (iB < eB) ? src[iB] : 0;
  while (iA < eA || iB < eB) {
    bool aA = iA < eA, aB = iB < eB;
    u16 wA = 0, dA = 0, wB = 0, dB = 0;
    u32x4 rA0 = {0,0,0,0}, rA1 = {0,0,0,0}, rB0 = {0,0,0,0}, rB1 = {0,0,0,0};
    int sAn = sA, sBn = sB;
    if (aA) {
      wA = wh[(size_t)iA * LE + l];
      dA = dinvh[(size_t)sA * LE + l];
      const u32x4* q = (const u32x4*)(xb + (size_t)sA * LN);
      rA0 = q[0]; rA1 = q[1];
      if (iA + 1 < eA) sAn = src[iA + 1];
    }
    if (aB) {
      wB = wh[(size_t)iB * LE + l];
      dB = dinvh[(size_t)sB * LE + l];
      const u32x4* q = (const u32x4*)(xb + (size_t)sB * LN);
      rB0 = q[0]; rB1 = q[1];
      if (iB + 1 < eB) sBn = src[iB + 1];
    }
    unsigned cAu = hmulu(wA, dA);   // 0 when inactive
    unsigned cBu = hmulu(wB, dB);
    __half2 ca = u2h2(cAu | (cAu << 16));
    __half2 cb = u2h2(cBu | (cBu << 16));
    accA[0] = __hfma2(ca, u2h2(rA0[0]), accA[0]);
    accA[1] = __hfma2(ca, u2h2(rA0[1]), accA[1]);
    accA[2] = __hfma2(ca, u2h2(rA0[2]), accA[2]);
    accA[3] = __hfma2(ca, u2h2(rA0[3]), accA[3]);
    accA[4] = __hfma2(ca, u2h2(rA1[0]), accA[4]);
    accA[5] = __hfma2(ca, u2h2(rA1[1]), accA[5]);
    accA[6] = __hfma2(ca, u2h2(rA1[2]), accA[6]);
    accA[7] = __hfma2(ca, u2h2(rA1[3]), accA[7]);
    accB[0] = __hfma2(cb, u2h2(rB0[0]), accB[0]);
    accB[1] = __hfma2(cb, u2h2(rB0[1]), accB[1]);
    accB[2] = __hfma2(cb, u2h2(rB0[2]), accB[2]);
    accB[3] = __hfma2(cb, u2h2(rB0[3]), accB[3]);
    accB[4] = __hfma2(cb, u2h2(rB1[0]), accB[4]);
    accB[5] = __hfma2(cb, u2h2(rB1[1]), accB[5]);
    accB[6] = __hfma2(cb, u2h2(rB1[2]), accB[6]);
    accB[7] = __hfma2(cb, u2h2(rB1[3]), accB[7]);
    sA = sAn; sB = sBn;
    iA += aA ? 1 : 0;
    iB += aB ? 1 : 0;
  }
  if (v0) lds_epilogue(n0, r0, l, colb, accA, dinvh, xwh, bgcn, S);
  if (v1) lds_epilogue(n1, r0 + 1, l, colb, accB, dinvh, xwh, bgcn, S);
  __syncthreads();
  // ---- phase 2: y[16,128] tile = S @ Wn; wave w owns cols w*16..w*16+15 ----
  f32x4 acc2;
  acc2[0] = 0.f; acc2[1] = 0.f; acc2[2] = 0.f; acc2[3] = 0.f;
  const char* arow = (const char*)(S + (size_t)(lane & 15) * ST);
#pragma unroll 8
  for (int kt = 0; kt < 32; ++kt) {
    int aoff = kt * 64 + g * 16;
    int key = ((aoff >> 7) & 7) << 4;
    f16x8 a = *(const f16x8*)(arow + (aoff ^ key));
    f16x8 b = *(const f16x8*)(WnP + ((size_t)(w * 32 + kt) * 64 + lane) * 8);
    acc2 = __builtin_amdgcn_mfma_f32_16x16x32_f16(a, b, acc2, 0, 0, 0);
  }
  int col = w * 16 + (lane & 15);
  float bb = bn[col];
  int rb = (lane >> 4) * 4;
#pragma unroll
  for (int r = 0; r < 4; ++r) {
    int row = nblk + rb + r;
    if (row < N) y[(size_t)row * DOUT + col] = fmaxf(acc2[r] + bb, 0.f);
  }
}

extern "C" void kernel_launch(void* const* d_in, const int* in_sizes, int n_in,
                              void* d_out, int out_size, void* d_ws, size_t ws_size,
                              hipStream_t stream) {
  const float* x  = (const float*)d_in[0];
  const int*   ei = (const int*)d_in[1];
  const float* ea = (const float*)d_in[2];
  const float* Wg = (const float*)d_in[3];
  const float* bg = (const float*)d_in[4];
  const float* We = (const float*)d_in[5];
  const float* be = (const float*)d_in[6];
  const float* Wn = (const float*)d_in[7];
  const float* bn = (const float*)d_in[8];
  float* outp = (float*)d_out;
  int N = in_sizes[0] / DN;  // 50000
  int E = in_sizes[1] / 2;   // 800000

  char* p = (char*)d_ws;
  auto carve = [&](size_t bytes) {
    char* r = p;
    p += (bytes + 255) & ~(size_t)255;
    return (void*)r;
  };
  u16*   wh    = (u16*)carve((size_t)E * LE * 2);    // CSR-ordered latent weights, fp16
  u16*   xwh   = (u16*)carve((size_t)N * LN * 2);    // xW in fp16
  u16*   dinvh = (u16*)carve((size_t)N * LE * 2);    // dinv fp16
  u16*   WnP   = (u16*)carve((size_t)(LE * LN) * DOUT * 2);
  u16*   WgP   = (u16*)carve((size_t)DN * LN * 2);
  int*   offs  = (int*)carve((size_t)(N + 1) * 4);
  int*   cnt   = (int*)carve((size_t)N * 4);
  int*   rank  = (int*)carve((size_t)E * 4);         // per-edge rank within dest
  int*   src   = (int*)carve((size_t)E * 4);

  hipMemsetAsync(cnt, 0, (size_t)N * 4, stream);

  // CSR histogram + per-edge rank (the only atomic pass)
  k_count<<<(E + 255) / 256, 256, 0, stream>>>(ei, cnt, rank, E);
  // scan (block 0) + pack both weight matrices (blocks 1..17)
  k_scan_packb<<<18, 1024, 0, stream>>>(cnt, offs, N, Wg, WgP, Wn, WnP);
  // fused CSR-fill + edge MLP (atomic-free: pos = offs[dest] + rank[e])
  k_fill_mlp<<<(E + 255) / 256, 256, 0, stream>>>(ea, We, be, ei, rank, offs, src, wh, E);
  // dinv (blocks [0,DB)) + gemm1 x@Wg -> xwh fp16 (blocks [DB,DB+GB), 64 rows each)
  int DB = (N + 15) / 16, GB = (N + 63) / 64;
  k_dinv_gemm1<<<DB + GB, 256, 0, stream>>>(wh, offs, dinvh, N, DB, x, WgP, xwh);
  // fused aggregation + output MLP (16 nodes/block, 8 waves, LDS staging)
  k_mega<<<(N + 15) / 16, 512, 0, stream>>>(src, wh, dinvh, xwh, bg, offs, WnP, bn, outp, N);
}